// Round 2
// baseline (93.329 us; speedup 1.0000x reference)
//
#include <hip/hip_runtime.h>

// ContrastiveLoss on MI355X.
// Pipeline:
//   k1 normalize: feats fp32 [8192][128] -> nf bf16 (ws)
//   k2 fused: odd blocks = 64x64 MFMA tiles of S=nf@nf^T with fixed-max
//             sum-of-exp partials (col-split x4 * wave-col x2 = 8 slots,
//             diag skipped); even blocks = stream 256MB label -> pos_idx[8192]
//   k3 finalize: per row lse = M + log(sum of 8 partials); pos = nf_i.nf_p/T;
//                block partial sums of (lse - pos)
//   k4 reduce: mean -> d_out[0]
// ws usage: 2MB nf + 256KB lpart + 32KB pos_idx + 128B bpart ~= 2.3MB.

#define NN 8192
#define DD 128

typedef __bf16 bf16x8 __attribute__((ext_vector_type(8)));
typedef float f32x4 __attribute__((ext_vector_type(4)));
typedef unsigned int u32x4 __attribute__((ext_vector_type(4)));

constexpr float kM     = 1.0f / 0.07f;                    // fixed max bound (cos<=1)
constexpr float kScale = 1.4426950408889634f / 0.07f;     // log2(e)/T
constexpr float kLn2   = 0.6931471805599453f;

__device__ inline unsigned short f2bf(float f) {
  unsigned int u = __float_as_uint(f);
  unsigned int r = (u + 0x7FFFu + ((u >> 16) & 1u)) >> 16;  // RNE, no NaN inputs
  return (unsigned short)r;
}

// ---------------- k1: normalize rows, store bf16 ----------------
__global__ __launch_bounds__(256) void k_normalize(const float* __restrict__ feats,
                                                   unsigned short* __restrict__ nfb) {
  int tid = threadIdx.x;
  int lane = tid & 63;
  int row = blockIdx.x * 4 + (tid >> 6);
  float2 f = *(const float2*)(feats + (size_t)row * DD + lane * 2);
  float ss = f.x * f.x + f.y * f.y;
  #pragma unroll
  for (int m = 1; m < 64; m <<= 1) ss += __shfl_xor(ss, m);
  float rn = 1.0f / fmaxf(sqrtf(ss), 1e-8f);
  unsigned int lo = f2bf(f.x * rn), hi = f2bf(f.y * rn);
  *(unsigned int*)(nfb + (size_t)row * DD + lane * 2) = lo | (hi << 16);
}

// ---------------- k2: fused GEMM+LSE partials / label scan ----------------
__global__ __launch_bounds__(256) void k_fused(const unsigned short* __restrict__ nfb,
                                               const int* __restrict__ label,
                                               float* __restrict__ lpart,
                                               int* __restrict__ pos_idx) {
  __shared__ __align__(16) unsigned short ldsB[64 * DD];  // 16KB, XOR-swizzled rows
  int b = blockIdx.x;
  int tid = threadIdx.x;
  if (b & 1) {
    // ---- GEMM + sum-of-exp block: rows [r0,r0+64), cols [c0,c0+2048) ----
    int g = b >> 1;                  // 0..511
    int r0 = (g >> 2) * 64;
    int c0 = (g & 3) * 2048;
    int lane = tid & 63, w = tid >> 6;
    int wm = w >> 1, wn = w & 1;     // 2x2 wave grid
    int lg = lane >> 4;              // lane group 0..3
    int ll = lane & 15;

    // A fragments: row = ll within 16-row subtile, k = kc*32 + lg*8 .. +7
    bf16x8 afr[2][4];
    #pragma unroll
    for (int ms = 0; ms < 2; ms++) {
      const unsigned short* arow = nfb + (size_t)(r0 + wm * 32 + ms * 16 + ll) * DD + lg * 8;
      #pragma unroll
      for (int kc = 0; kc < 4; kc++)
        afr[ms][kc] = *(const bf16x8*)(arow + kc * 32);
    }

    float lacc[2][4] = {{0.f, 0.f, 0.f, 0.f}, {0.f, 0.f, 0.f, 0.f}};
    int slr = tid >> 4;   // staging: local row base
    int sch = tid & 15;   // staging: 16B chunk

    for (int ct = 0; ct < 32; ct++) {
      int ctile = c0 + ct * 64;
      __syncthreads();
      // stage 64x128 bf16 B tile (rows = global cols), swizzled
      #pragma unroll
      for (int p = 0; p < 4; p++) {
        int row = p * 16 + slr;
        u32x4 v = *(const u32x4*)(nfb + (size_t)(ctile + row) * DD + sch * 8);
        *(u32x4*)((char*)ldsB + row * 256 + ((sch * 16) ^ ((row & 7) << 4))) = v;
      }
      __syncthreads();

      f32x4 acc[2][2] = {{{0.f,0.f,0.f,0.f},{0.f,0.f,0.f,0.f}},
                         {{0.f,0.f,0.f,0.f},{0.f,0.f,0.f,0.f}}};
      #pragma unroll
      for (int ns = 0; ns < 2; ns++) {
        int brow = wn * 32 + ns * 16 + ll;
        const char* bbase = (const char*)ldsB + brow * 256;
        int sw = (brow & 7) << 4;
        #pragma unroll
        for (int kc = 0; kc < 4; kc++) {
          bf16x8 bfr = *(const bf16x8*)(bbase + ((kc * 64 + lg * 16) ^ sw));
          acc[0][ns] = __builtin_amdgcn_mfma_f32_16x16x32_bf16(afr[0][kc], bfr, acc[0][ns], 0, 0, 0);
          acc[1][ns] = __builtin_amdgcn_mfma_f32_16x16x32_bf16(afr[1][kc], bfr, acc[1][ns], 0, 0, 0);
        }
      }

      // sum exp(z - M) with fixed M=1/T; C layout: col=ll, row=lg*4+r
      bool mayDiag = (ctile < r0 + 64) && (r0 < ctile + 64);
      if (mayDiag) {
        #pragma unroll
        for (int ms = 0; ms < 2; ms++) {
          int growb = r0 + wm * 32 + ms * 16 + lg * 4;
          #pragma unroll
          for (int ns = 0; ns < 2; ns++) {
            int gcol = ctile + wn * 32 + ns * 16 + ll;
            #pragma unroll
            for (int r = 0; r < 4; r++) {
              float s = (growb + r == gcol) ? -3.0e38f : acc[ms][ns][r];
              lacc[ms][r] += __builtin_amdgcn_exp2f((s - 1.0f) * kScale);
            }
          }
        }
      } else {
        #pragma unroll
        for (int ms = 0; ms < 2; ms++)
          #pragma unroll
          for (int ns = 0; ns < 2; ns++)
            #pragma unroll
            for (int r = 0; r < 4; r++)
              lacc[ms][r] += __builtin_amdgcn_exp2f((acc[ms][ns][r] - 1.0f) * kScale);
      }
    }

    // reduce partial l across the 16 lanes of each group (cols), write per row.
    // NOTE: wn=0 and wn=1 waves each hold HALF the strip's columns for the same
    // rows -> they must write DISTINCT slots (slot = (g&3)*2 + wn), summed in k3.
    #pragma unroll
    for (int ms = 0; ms < 2; ms++)
      #pragma unroll
      for (int r = 0; r < 4; r++) {
        float v = lacc[ms][r];
        v += __shfl_xor(v, 1); v += __shfl_xor(v, 2);
        v += __shfl_xor(v, 4); v += __shfl_xor(v, 8);
        lacc[ms][r] = v;
      }
    if (ll == 0) {
      int slot = (g & 3) * 2 + wn;
      #pragma unroll
      for (int ms = 0; ms < 2; ms++)
        #pragma unroll
        for (int r = 0; r < 4; r++) {
          int grow = r0 + wm * 32 + ms * 16 + lg * 4 + r;
          lpart[(size_t)slot * NN + grow] = lacc[ms][r];
        }
    }
  } else {
    // ---- label scan block: find the single 1 per row ----
    int sg = b >> 1;                         // 0..511
    const u32x4* L = (const u32x4*)label;
    int t = sg * 256 + tid;                  // 131072 scan threads
    for (int k = 0; k < 128; k++) {
      int idx = t + k * 131072;
      u32x4 v = __builtin_nontemporal_load(&L[idx]);
      if (v[0] | v[1] | v[2] | v[3]) {
        int gi = idx * 4;
        int row = gi >> 13, col = gi & (NN - 1);
        if (v[0] == 1u) pos_idx[row] = col;
        if (v[1] == 1u) pos_idx[row] = col + 1;
        if (v[2] == 1u) pos_idx[row] = col + 2;
        if (v[3] == 1u) pos_idx[row] = col + 3;
      }
    }
  }
}

// ---------------- k3: per-row lse + positive, block partial sums ----------------
__global__ __launch_bounds__(256) void k_finalize(const unsigned short* __restrict__ nfb,
                                                  const float* __restrict__ lpart,
                                                  const int* __restrict__ pos_idx,
                                                  float* __restrict__ bpart) {
  int i = blockIdx.x * 256 + threadIdx.x;
  float l = 0.f;
  #pragma unroll
  for (int s = 0; s < 8; s++) l += lpart[(size_t)s * NN + i];
  float lse = kM + __builtin_amdgcn_logf(l) * kLn2;
  int p = pos_idx[i] & (NN - 1);
  const u32x4* ri = (const u32x4*)(nfb + (size_t)i * DD);
  const u32x4* rp = (const u32x4*)(nfb + (size_t)p * DD);
  float dot = 0.f;
  #pragma unroll
  for (int c = 0; c < 16; c++) {
    u32x4 a = ri[c], bb = rp[c];
    #pragma unroll
    for (int e = 0; e < 4; e++) {
      float al = __uint_as_float(a[e] << 16), ah = __uint_as_float(a[e] & 0xFFFF0000u);
      float bl = __uint_as_float(bb[e] << 16), bh = __uint_as_float(bb[e] & 0xFFFF0000u);
      dot += al * bl + ah * bh;
    }
  }
  float val = lse - dot * kM;   // pos = dot / T
  #pragma unroll
  for (int m = 1; m < 64; m <<= 1) val += __shfl_xor(val, m);
  __shared__ float wsum[4];
  if ((threadIdx.x & 63) == 0) wsum[threadIdx.x >> 6] = val;
  __syncthreads();
  if (threadIdx.x == 0) bpart[blockIdx.x] = wsum[0] + wsum[1] + wsum[2] + wsum[3];
}

// ---------------- k4: final mean ----------------
__global__ void k_reduce(const float* __restrict__ bpart, float* __restrict__ out) {
  int t = threadIdx.x;
  float v = (t < 32) ? bpart[t] : 0.f;
  #pragma unroll
  for (int m = 1; m < 64; m <<= 1) v += __shfl_xor(v, m);
  if (t == 0) out[0] = v * (1.0f / (float)NN);
}

extern "C" void kernel_launch(void* const* d_in, const int* in_sizes, int n_in,
                              void* d_out, int out_size, void* d_ws, size_t ws_size,
                              hipStream_t stream) {
  (void)in_sizes; (void)n_in; (void)out_size; (void)ws_size;
  const float* feats = (const float*)d_in[0];
  const int* label = (const int*)d_in[1];
  float* out = (float*)d_out;

  char* ws = (char*)d_ws;
  unsigned short* nfb = (unsigned short*)ws;                    // 2 MB
  float* lpart = (float*)(ws + 2 * 1024 * 1024);                // 256 KB (8 slots)
  int* pos_idx = (int*)(ws + 2 * 1024 * 1024 + 262144);         // 32 KB
  float* bpart = (float*)(ws + 2 * 1024 * 1024 + 262144 + 32768);

  k_normalize<<<NN / 4, 256, 0, stream>>>(feats, nfb);
  k_fused<<<1024, 256, 0, stream>>>(nfb, label, lpart, pos_idx);
  k_finalize<<<NN / 256, 256, 0, stream>>>(nfb, lpart, pos_idx, bpart);
  k_reduce<<<1, 64, 0, stream>>>(bpart, out);
}

// Round 3
// 72.202 us; speedup vs baseline: 1.2926x; 1.2926x over previous
//
#include <hip/hip_runtime.h>

// ContrastiveLoss on MI355X.
// Pipeline:
//   k1 normalize: feats fp32 [8192][128] -> nf bf16 (ws)
//   k2 fused: odd blocks = 64x64 MFMA tiles of S=nf@nf^T with fixed-max
//             sum-of-exp partials (col-split x4 * wave-col x2 = 8 slots,
//             diag skipped); even blocks = stream 256MB label -> pos_idx[8192]
//             (8-deep load batches for latency hiding)
//   k3 finalize: per row lse = M + log(sum of 8 partials); pos = nf_i.nf_p/T;
//                block partial sums of (lse - pos)
//   k4 reduce: mean -> d_out[0]
// ws usage: 2MB nf + 256KB lpart + 32KB pos_idx + 128B bpart ~= 2.3MB.

#define NN 8192
#define DD 128

typedef __bf16 bf16x8 __attribute__((ext_vector_type(8)));
typedef float f32x4 __attribute__((ext_vector_type(4)));
typedef unsigned int u32x4 __attribute__((ext_vector_type(4)));

constexpr float kM     = 1.0f / 0.07f;                    // fixed max bound (cos<=1)
constexpr float kScale = 1.4426950408889634f / 0.07f;     // log2(e)/T
constexpr float kLn2   = 0.6931471805599453f;

__device__ inline unsigned short f2bf(float f) {
  unsigned int u = __float_as_uint(f);
  unsigned int r = (u + 0x7FFFu + ((u >> 16) & 1u)) >> 16;  // RNE, no NaN inputs
  return (unsigned short)r;
}

// ---------------- k1: normalize rows, store bf16 ----------------
__global__ __launch_bounds__(256) void k_normalize(const float* __restrict__ feats,
                                                   unsigned short* __restrict__ nfb) {
  int tid = threadIdx.x;
  int lane = tid & 63;
  int row = blockIdx.x * 4 + (tid >> 6);
  float2 f = *(const float2*)(feats + (size_t)row * DD + lane * 2);
  float ss = f.x * f.x + f.y * f.y;
  #pragma unroll
  for (int m = 1; m < 64; m <<= 1) ss += __shfl_xor(ss, m);
  float rn = 1.0f / fmaxf(sqrtf(ss), 1e-8f);
  unsigned int lo = f2bf(f.x * rn), hi = f2bf(f.y * rn);
  *(unsigned int*)(nfb + (size_t)row * DD + lane * 2) = lo | (hi << 16);
}

// ---------------- k2: fused GEMM+LSE partials / label scan ----------------
__global__ __launch_bounds__(256) void k_fused(const unsigned short* __restrict__ nfb,
                                               const int* __restrict__ label,
                                               float* __restrict__ lpart,
                                               int* __restrict__ pos_idx) {
  __shared__ __align__(16) unsigned short ldsB[64 * DD];  // 16KB, XOR-swizzled rows
  int b = blockIdx.x;
  int tid = threadIdx.x;
  if (b & 1) {
    // ---- GEMM + sum-of-exp block: rows [r0,r0+64), cols [c0,c0+2048) ----
    int g = b >> 1;                  // 0..511
    int r0 = (g >> 2) * 64;
    int c0 = (g & 3) * 2048;
    int lane = tid & 63, w = tid >> 6;
    int wm = w >> 1, wn = w & 1;     // 2x2 wave grid
    int lg = lane >> 4;              // lane group 0..3
    int ll = lane & 15;

    // A fragments: row = ll within 16-row subtile, k = kc*32 + lg*8 .. +7
    bf16x8 afr[2][4];
    #pragma unroll
    for (int ms = 0; ms < 2; ms++) {
      const unsigned short* arow = nfb + (size_t)(r0 + wm * 32 + ms * 16 + ll) * DD + lg * 8;
      #pragma unroll
      for (int kc = 0; kc < 4; kc++)
        afr[ms][kc] = *(const bf16x8*)(arow + kc * 32);
    }

    float lacc[2][4] = {{0.f, 0.f, 0.f, 0.f}, {0.f, 0.f, 0.f, 0.f}};
    int slr = tid >> 4;   // staging: local row base
    int sch = tid & 15;   // staging: 16B chunk

    for (int ct = 0; ct < 32; ct++) {
      int ctile = c0 + ct * 64;
      __syncthreads();
      // stage 64x128 bf16 B tile (rows = global cols), swizzled
      #pragma unroll
      for (int p = 0; p < 4; p++) {
        int row = p * 16 + slr;
        u32x4 v = *(const u32x4*)(nfb + (size_t)(ctile + row) * DD + sch * 8);
        *(u32x4*)((char*)ldsB + row * 256 + ((sch * 16) ^ ((row & 7) << 4))) = v;
      }
      __syncthreads();

      f32x4 acc[2][2] = {{{0.f,0.f,0.f,0.f},{0.f,0.f,0.f,0.f}},
                         {{0.f,0.f,0.f,0.f},{0.f,0.f,0.f,0.f}}};
      #pragma unroll
      for (int ns = 0; ns < 2; ns++) {
        int brow = wn * 32 + ns * 16 + ll;
        const char* bbase = (const char*)ldsB + brow * 256;
        int sw = (brow & 7) << 4;
        #pragma unroll
        for (int kc = 0; kc < 4; kc++) {
          bf16x8 bfr = *(const bf16x8*)(bbase + ((kc * 64 + lg * 16) ^ sw));
          acc[0][ns] = __builtin_amdgcn_mfma_f32_16x16x32_bf16(afr[0][kc], bfr, acc[0][ns], 0, 0, 0);
          acc[1][ns] = __builtin_amdgcn_mfma_f32_16x16x32_bf16(afr[1][kc], bfr, acc[1][ns], 0, 0, 0);
        }
      }

      // sum exp(z - M) with fixed M=1/T; C layout: col=ll, row=lg*4+r
      bool mayDiag = (ctile < r0 + 64) && (r0 < ctile + 64);
      if (mayDiag) {
        #pragma unroll
        for (int ms = 0; ms < 2; ms++) {
          int growb = r0 + wm * 32 + ms * 16 + lg * 4;
          #pragma unroll
          for (int ns = 0; ns < 2; ns++) {
            int gcol = ctile + wn * 32 + ns * 16 + ll;
            #pragma unroll
            for (int r = 0; r < 4; r++) {
              float s = (growb + r == gcol) ? -3.0e38f : acc[ms][ns][r];
              lacc[ms][r] += __builtin_amdgcn_exp2f((s - 1.0f) * kScale);
            }
          }
        }
      } else {
        #pragma unroll
        for (int ms = 0; ms < 2; ms++)
          #pragma unroll
          for (int ns = 0; ns < 2; ns++)
            #pragma unroll
            for (int r = 0; r < 4; r++)
              lacc[ms][r] += __builtin_amdgcn_exp2f((acc[ms][ns][r] - 1.0f) * kScale);
      }
    }

    // reduce partial l across the 16 lanes of each group (cols), write per row.
    // wn=0/wn=1 hold disjoint column halves for the same rows -> distinct slots.
    #pragma unroll
    for (int ms = 0; ms < 2; ms++)
      #pragma unroll
      for (int r = 0; r < 4; r++) {
        float v = lacc[ms][r];
        v += __shfl_xor(v, 1); v += __shfl_xor(v, 2);
        v += __shfl_xor(v, 4); v += __shfl_xor(v, 8);
        lacc[ms][r] = v;
      }
    if (ll == 0) {
      int slot = (g & 3) * 2 + wn;
      #pragma unroll
      for (int ms = 0; ms < 2; ms++)
        #pragma unroll
        for (int r = 0; r < 4; r++) {
          int grow = r0 + wm * 32 + ms * 16 + lg * 4 + r;
          lpart[(size_t)slot * NN + grow] = lacc[ms][r];
        }
    }
  } else {
    // ---- label scan block: find the single 1 per row ----
    // 8-deep load batches: 8 independent nontemporal u32x4 loads in flight
    // per lane (128B), then one OR-test; fine-grained check only when hit
    // (~one positive per 8192-int row -> taken for ~22% of waves per batch).
    int sg = b >> 1;                         // 0..511
    const u32x4* L = (const u32x4*)label;
    int t = sg * 256 + tid;                  // 131072 scan threads
    for (int k = 0; k < 16; k++) {
      u32x4 v[8];
      #pragma unroll
      for (int j = 0; j < 8; j++)
        v[j] = __builtin_nontemporal_load(&L[t + (k * 8 + j) * 131072]);
      unsigned any = 0;
      #pragma unroll
      for (int j = 0; j < 8; j++) any |= v[j][0] | v[j][1] | v[j][2] | v[j][3];
      if (any) {
        #pragma unroll
        for (int j = 0; j < 8; j++) {
          int idx = t + (k * 8 + j) * 131072;
          if (v[j][0] | v[j][1] | v[j][2] | v[j][3]) {
            int gi = idx * 4;
            int row = gi >> 13, col = gi & (NN - 1);
            if (v[j][0] == 1u) pos_idx[row] = col;
            if (v[j][1] == 1u) pos_idx[row] = col + 1;
            if (v[j][2] == 1u) pos_idx[row] = col + 2;
            if (v[j][3] == 1u) pos_idx[row] = col + 3;
          }
        }
      }
    }
  }
}

// ---------------- k3: per-row lse + positive, block partial sums ----------------
__global__ __launch_bounds__(256) void k_finalize(const unsigned short* __restrict__ nfb,
                                                  const float* __restrict__ lpart,
                                                  const int* __restrict__ pos_idx,
                                                  float* __restrict__ bpart) {
  int i = blockIdx.x * 256 + threadIdx.x;
  float l = 0.f;
  #pragma unroll
  for (int s = 0; s < 8; s++) l += lpart[(size_t)s * NN + i];
  float lse = kM + __builtin_amdgcn_logf(l) * kLn2;
  int p = pos_idx[i] & (NN - 1);
  const u32x4* ri = (const u32x4*)(nfb + (size_t)i * DD);
  const u32x4* rp = (const u32x4*)(nfb + (size_t)p * DD);
  float dot = 0.f;
  #pragma unroll
  for (int c = 0; c < 16; c++) {
    u32x4 a = ri[c], bb = rp[c];
    #pragma unroll
    for (int e = 0; e < 4; e++) {
      float al = __uint_as_float(a[e] << 16), ah = __uint_as_float(a[e] & 0xFFFF0000u);
      float bl = __uint_as_float(bb[e] << 16), bh = __uint_as_float(bb[e] & 0xFFFF0000u);
      dot += al * bl + ah * bh;
    }
  }
  float val = lse - dot * kM;   // pos = dot / T
  #pragma unroll
  for (int m = 1; m < 64; m <<= 1) val += __shfl_xor(val, m);
  __shared__ float wsum[4];
  if ((threadIdx.x & 63) == 0) wsum[threadIdx.x >> 6] = val;
  __syncthreads();
  if (threadIdx.x == 0) bpart[blockIdx.x] = wsum[0] + wsum[1] + wsum[2] + wsum[3];
}

// ---------------- k4: final mean ----------------
__global__ void k_reduce(const float* __restrict__ bpart, float* __restrict__ out) {
  int t = threadIdx.x;
  float v = (t < 32) ? bpart[t] : 0.f;
  #pragma unroll
  for (int m = 1; m < 64; m <<= 1) v += __shfl_xor(v, m);
  if (t == 0) out[0] = v * (1.0f / (float)NN);
}

extern "C" void kernel_launch(void* const* d_in, const int* in_sizes, int n_in,
                              void* d_out, int out_size, void* d_ws, size_t ws_size,
                              hipStream_t stream) {
  (void)in_sizes; (void)n_in; (void)out_size; (void)ws_size;
  const float* feats = (const float*)d_in[0];
  const int* label = (const int*)d_in[1];
  float* out = (float*)d_out;

  char* ws = (char*)d_ws;
  unsigned short* nfb = (unsigned short*)ws;                    // 2 MB
  float* lpart = (float*)(ws + 2 * 1024 * 1024);                // 256 KB (8 slots)
  int* pos_idx = (int*)(ws + 2 * 1024 * 1024 + 262144);         // 32 KB
  float* bpart = (float*)(ws + 2 * 1024 * 1024 + 262144 + 32768);

  k_normalize<<<NN / 4, 256, 0, stream>>>(feats, nfb);
  k_fused<<<1024, 256, 0, stream>>>(nfb, label, lpart, pos_idx);
  k_finalize<<<NN / 256, 256, 0, stream>>>(nfb, lpart, pos_idx, bpart);
  k_reduce<<<1, 64, 0, stream>>>(bpart, out);
}

// Round 4
// 71.284 us; speedup vs baseline: 1.3093x; 1.0129x over previous
//
#include <hip/hip_runtime.h>

// ContrastiveLoss on MI355X.
// Pipeline:
//   k1 normalize: feats fp32 [8192][128] -> nf bf16 (ws)
//   k2 fused: blocks with (b&8)!=0 = 64x64 MFMA tiles of S=nf@nf^T with
//             fixed-max sum-of-exp partials (col-split x4 * wave-col x2 = 8
//             slots, diag skipped); blocks with (b&8)==0 = stream 256MB label
//             -> pos_idx[8192] (8-deep load batches).
//             Discriminator is BIT 3 (not bit 0): workgroup->XCD assignment
//             round-robins blockIdx%8, so a bit-0 split segregates scan and
//             GEMM onto disjoint XCDs (label stream through only 4 XCDs'
//             fabric -> ~4 TB/s cap). Bit 3 interleaves both types on every
//             XCD -> full-width HBM for the scan, all 256 CUs for the GEMM.
//   k3 finalize: per row lse = M + log(sum of 8 partials); pos = nf_i.nf_p/T;
//                block partial sums of (lse - pos)
//   k4 reduce: mean -> d_out[0]
// ws usage: 2MB nf + 256KB lpart + 32KB pos_idx + 128B bpart ~= 2.3MB.

#define NN 8192
#define DD 128

typedef __bf16 bf16x8 __attribute__((ext_vector_type(8)));
typedef float f32x4 __attribute__((ext_vector_type(4)));
typedef unsigned int u32x4 __attribute__((ext_vector_type(4)));

constexpr float kM     = 1.0f / 0.07f;                    // fixed max bound (cos<=1)
constexpr float kScale = 1.4426950408889634f / 0.07f;     // log2(e)/T
constexpr float kLn2   = 0.6931471805599453f;

__device__ inline unsigned short f2bf(float f) {
  unsigned int u = __float_as_uint(f);
  unsigned int r = (u + 0x7FFFu + ((u >> 16) & 1u)) >> 16;  // RNE, no NaN inputs
  return (unsigned short)r;
}

// ---------------- k1: normalize rows, store bf16 ----------------
__global__ __launch_bounds__(256) void k_normalize(const float* __restrict__ feats,
                                                   unsigned short* __restrict__ nfb) {
  int tid = threadIdx.x;
  int lane = tid & 63;
  int row = blockIdx.x * 4 + (tid >> 6);
  float2 f = *(const float2*)(feats + (size_t)row * DD + lane * 2);
  float ss = f.x * f.x + f.y * f.y;
  #pragma unroll
  for (int m = 1; m < 64; m <<= 1) ss += __shfl_xor(ss, m);
  float rn = 1.0f / fmaxf(sqrtf(ss), 1e-8f);
  unsigned int lo = f2bf(f.x * rn), hi = f2bf(f.y * rn);
  *(unsigned int*)(nfb + (size_t)row * DD + lane * 2) = lo | (hi << 16);
}

// ---------------- k2: fused GEMM+LSE partials / label scan ----------------
__global__ __launch_bounds__(256) void k_fused(const unsigned short* __restrict__ nfb,
                                               const int* __restrict__ label,
                                               float* __restrict__ lpart,
                                               int* __restrict__ pos_idx) {
  __shared__ __align__(16) unsigned short ldsB[64 * DD];  // 16KB, XOR-swizzled rows
  int b = blockIdx.x;
  int tid = threadIdx.x;
  // sub-index within this block's type: groups of 8 alternate scan/GEMM
  int sub = ((b >> 4) << 3) | (b & 7);       // 0..511 for each type
  if (b & 8) {
    // ---- GEMM + sum-of-exp block: rows [r0,r0+64), cols [c0,c0+2048) ----
    int g = sub;                     // 0..511
    int r0 = (g >> 2) * 64;
    int c0 = (g & 3) * 2048;
    int lane = tid & 63, w = tid >> 6;
    int wm = w >> 1, wn = w & 1;     // 2x2 wave grid
    int lg = lane >> 4;              // lane group 0..3
    int ll = lane & 15;

    // A fragments: row = ll within 16-row subtile, k = kc*32 + lg*8 .. +7
    bf16x8 afr[2][4];
    #pragma unroll
    for (int ms = 0; ms < 2; ms++) {
      const unsigned short* arow = nfb + (size_t)(r0 + wm * 32 + ms * 16 + ll) * DD + lg * 8;
      #pragma unroll
      for (int kc = 0; kc < 4; kc++)
        afr[ms][kc] = *(const bf16x8*)(arow + kc * 32);
    }

    float lacc[2][4] = {{0.f, 0.f, 0.f, 0.f}, {0.f, 0.f, 0.f, 0.f}};
    int slr = tid >> 4;   // staging: local row base
    int sch = tid & 15;   // staging: 16B chunk

    for (int ct = 0; ct < 32; ct++) {
      int ctile = c0 + ct * 64;
      __syncthreads();
      // stage 64x128 bf16 B tile (rows = global cols), swizzled
      #pragma unroll
      for (int p = 0; p < 4; p++) {
        int row = p * 16 + slr;
        u32x4 v = *(const u32x4*)(nfb + (size_t)(ctile + row) * DD + sch * 8);
        *(u32x4*)((char*)ldsB + row * 256 + ((sch * 16) ^ ((row & 7) << 4))) = v;
      }
      __syncthreads();

      f32x4 acc[2][2] = {{{0.f,0.f,0.f,0.f},{0.f,0.f,0.f,0.f}},
                         {{0.f,0.f,0.f,0.f},{0.f,0.f,0.f,0.f}}};
      #pragma unroll
      for (int ns = 0; ns < 2; ns++) {
        int brow = wn * 32 + ns * 16 + ll;
        const char* bbase = (const char*)ldsB + brow * 256;
        int sw = (brow & 7) << 4;
        #pragma unroll
        for (int kc = 0; kc < 4; kc++) {
          bf16x8 bfr = *(const bf16x8*)(bbase + ((kc * 64 + lg * 16) ^ sw));
          acc[0][ns] = __builtin_amdgcn_mfma_f32_16x16x32_bf16(afr[0][kc], bfr, acc[0][ns], 0, 0, 0);
          acc[1][ns] = __builtin_amdgcn_mfma_f32_16x16x32_bf16(afr[1][kc], bfr, acc[1][ns], 0, 0, 0);
        }
      }

      // sum exp(z - M) with fixed M=1/T; C layout: col=ll, row=lg*4+r
      bool mayDiag = (ctile < r0 + 64) && (r0 < ctile + 64);
      if (mayDiag) {
        #pragma unroll
        for (int ms = 0; ms < 2; ms++) {
          int growb = r0 + wm * 32 + ms * 16 + lg * 4;
          #pragma unroll
          for (int ns = 0; ns < 2; ns++) {
            int gcol = ctile + wn * 32 + ns * 16 + ll;
            #pragma unroll
            for (int r = 0; r < 4; r++) {
              float s = (growb + r == gcol) ? -3.0e38f : acc[ms][ns][r];
              lacc[ms][r] += __builtin_amdgcn_exp2f((s - 1.0f) * kScale);
            }
          }
        }
      } else {
        #pragma unroll
        for (int ms = 0; ms < 2; ms++)
          #pragma unroll
          for (int ns = 0; ns < 2; ns++)
            #pragma unroll
            for (int r = 0; r < 4; r++)
              lacc[ms][r] += __builtin_amdgcn_exp2f((acc[ms][ns][r] - 1.0f) * kScale);
      }
    }

    // reduce partial l across the 16 lanes of each group (cols), write per row.
    // wn=0/wn=1 hold disjoint column halves for the same rows -> distinct slots.
    #pragma unroll
    for (int ms = 0; ms < 2; ms++)
      #pragma unroll
      for (int r = 0; r < 4; r++) {
        float v = lacc[ms][r];
        v += __shfl_xor(v, 1); v += __shfl_xor(v, 2);
        v += __shfl_xor(v, 4); v += __shfl_xor(v, 8);
        lacc[ms][r] = v;
      }
    if (ll == 0) {
      int slot = (g & 3) * 2 + wn;
      #pragma unroll
      for (int ms = 0; ms < 2; ms++)
        #pragma unroll
        for (int r = 0; r < 4; r++) {
          int grow = r0 + wm * 32 + ms * 16 + lg * 4 + r;
          lpart[(size_t)slot * NN + grow] = lacc[ms][r];
        }
    }
  } else {
    // ---- label scan block: find the single 1 per row ----
    // 8-deep load batches: 8 independent nontemporal u32x4 loads in flight
    // per lane (128B), then one OR-test; fine-grained check only when hit.
    int sg = sub;                            // 0..511
    const u32x4* L = (const u32x4*)label;
    int t = sg * 256 + tid;                  // 131072 scan threads
    for (int k = 0; k < 16; k++) {
      u32x4 v[8];
      #pragma unroll
      for (int j = 0; j < 8; j++)
        v[j] = __builtin_nontemporal_load(&L[t + (k * 8 + j) * 131072]);
      unsigned any = 0;
      #pragma unroll
      for (int j = 0; j < 8; j++) any |= v[j][0] | v[j][1] | v[j][2] | v[j][3];
      if (any) {
        #pragma unroll
        for (int j = 0; j < 8; j++) {
          int idx = t + (k * 8 + j) * 131072;
          if (v[j][0] | v[j][1] | v[j][2] | v[j][3]) {
            int gi = idx * 4;
            int row = gi >> 13, col = gi & (NN - 1);
            if (v[j][0] == 1u) pos_idx[row] = col;
            if (v[j][1] == 1u) pos_idx[row] = col + 1;
            if (v[j][2] == 1u) pos_idx[row] = col + 2;
            if (v[j][3] == 1u) pos_idx[row] = col + 3;
          }
        }
      }
    }
  }
}

// ---------------- k3: per-row lse + positive, block partial sums ----------------
__global__ __launch_bounds__(256) void k_finalize(const unsigned short* __restrict__ nfb,
                                                  const float* __restrict__ lpart,
                                                  const int* __restrict__ pos_idx,
                                                  float* __restrict__ bpart) {
  int i = blockIdx.x * 256 + threadIdx.x;
  float l = 0.f;
  #pragma unroll
  for (int s = 0; s < 8; s++) l += lpart[(size_t)s * NN + i];
  float lse = kM + __builtin_amdgcn_logf(l) * kLn2;
  int p = pos_idx[i] & (NN - 1);
  const u32x4* ri = (const u32x4*)(nfb + (size_t)i * DD);
  const u32x4* rp = (const u32x4*)(nfb + (size_t)p * DD);
  float dot = 0.f;
  #pragma unroll
  for (int c = 0; c < 16; c++) {
    u32x4 a = ri[c], bb = rp[c];
    #pragma unroll
    for (int e = 0; e < 4; e++) {
      float al = __uint_as_float(a[e] << 16), ah = __uint_as_float(a[e] & 0xFFFF0000u);
      float bl = __uint_as_float(bb[e] << 16), bh = __uint_as_float(bb[e] & 0xFFFF0000u);
      dot += al * bl + ah * bh;
    }
  }
  float val = lse - dot * kM;   // pos = dot / T
  #pragma unroll
  for (int m = 1; m < 64; m <<= 1) val += __shfl_xor(val, m);
  __shared__ float wsum[4];
  if ((threadIdx.x & 63) == 0) wsum[threadIdx.x >> 6] = val;
  __syncthreads();
  if (threadIdx.x == 0) bpart[blockIdx.x] = wsum[0] + wsum[1] + wsum[2] + wsum[3];
}

// ---------------- k4: final mean ----------------
__global__ void k_reduce(const float* __restrict__ bpart, float* __restrict__ out) {
  int t = threadIdx.x;
  float v = (t < 32) ? bpart[t] : 0.f;
  #pragma unroll
  for (int m = 1; m < 64; m <<= 1) v += __shfl_xor(v, m);
  if (t == 0) out[0] = v * (1.0f / (float)NN);
}

extern "C" void kernel_launch(void* const* d_in, const int* in_sizes, int n_in,
                              void* d_out, int out_size, void* d_ws, size_t ws_size,
                              hipStream_t stream) {
  (void)in_sizes; (void)n_in; (void)out_size; (void)ws_size;
  const float* feats = (const float*)d_in[0];
  const int* label = (const int*)d_in[1];
  float* out = (float*)d_out;

  char* ws = (char*)d_ws;
  unsigned short* nfb = (unsigned short*)ws;                    // 2 MB
  float* lpart = (float*)(ws + 2 * 1024 * 1024);                // 256 KB (8 slots)
  int* pos_idx = (int*)(ws + 2 * 1024 * 1024 + 262144);         // 32 KB
  float* bpart = (float*)(ws + 2 * 1024 * 1024 + 262144 + 32768);

  k_normalize<<<NN / 4, 256, 0, stream>>>(feats, nfb);
  k_fused<<<1024, 256, 0, stream>>>(nfb, label, lpart, pos_idx);
  k_finalize<<<NN / 256, 256, 0, stream>>>(nfb, lpart, pos_idx, bpart);
  k_reduce<<<1, 64, 0, stream>>>(bpart, out);
}